// Round 10
// baseline (432.121 us; speedup 1.0000x reference)
//
#include <hip/hip_runtime.h>

typedef __bf16 bf16x8 __attribute__((ext_vector_type(8)));
typedef __bf16 bf16x4 __attribute__((ext_vector_type(4)));
typedef float floatx4 __attribute__((ext_vector_type(4)));

#define EMB 1024
#define MROWS 4096
#define HIDN 4096
#define PSTRIDE ((size_t)MROWS * EMB)   // partial-slice stride (elements)

// ---------------------------------------------------------------- helpers
__device__ __forceinline__ void load_lds16(const __bf16* g, __bf16* l) {
    __builtin_amdgcn_global_load_lds(
        (const __attribute__((address_space(1))) void*)g,
        (__attribute__((address_space(3))) void*)l, 16, 0, 0);
}

// ----------------------- batched fp32->bf16 transposes (16 jobs, 1 dispatch)
struct TJobs { const float* s[16]; __bf16* d[16]; int sld[16]; int dld[16]; };
__global__ void transpose_cast16_kernel(TJobs a) {
    __shared__ float tile[32][33];
    int jz = blockIdx.z;
    const float* in = a.s[jz];
    __bf16* out = a.d[jz];
    int sld = a.sld[jz], dld = a.dld[jz];
    int tx = threadIdx.x, ty = threadIdx.y;
    int c0 = blockIdx.x * 32, r0 = blockIdx.y * 32;
#pragma unroll
    for (int i = 0; i < 32; i += 8)
        tile[ty + i][tx] = in[(size_t)(r0 + ty + i) * sld + c0 + tx];
    __syncthreads();
#pragma unroll
    for (int i = 0; i < 32; i += 8)
        out[(size_t)(c0 + ty + i) * dld + r0 + tx] = (__bf16)tile[tx][ty + i];
}

// ------------------------------------ fp32 -> bf16 cast, two tensors/launch
__global__ void cast2_bf16_kernel(const float* __restrict__ a,
                                  const float* __restrict__ b,
                                  __bf16* __restrict__ oa,
                                  __bf16* __restrict__ ob, int n) {
    int i = (blockIdx.x * 256 + threadIdx.x) * 4;
    const float* in = a;
    __bf16* out = oa;
    if (i >= n) { i -= n; in = b; out = ob; }
    float4 v = *(const float4*)(in + i);
    bf16x4 o;
    o[0] = (__bf16)v.x; o[1] = (__bf16)v.y; o[2] = (__bf16)v.z; o[3] = (__bf16)v.w;
    *(bf16x4*)(out + i) = o;
}

// ------------------------------------------------------------- GEMM (NT)
// 128x128-tile kernel for split-K short-K GEMMs (attn proj): REG=1
// register-prefetch path. Proven 13us/dispatch at z=2 (R3 dataflow).
template <int RELU, int REG>
__launch_bounds__(256, 4)
__global__ void gemm_bt(const __bf16* __restrict__ A, const __bf16* __restrict__ A2,
                        int asplit, const __bf16* __restrict__ Bt,
                        __bf16* __restrict__ cb, __bf16* __restrict__ cbalt,
                        const float* __restrict__ bias,
                        int M, int N, int Kd, float scale0, float scale1,
                        int split, int fx, int fy) {
    __shared__ alignas(16) __bf16 smem[2 * 128 * 32];
    __bf16* As = smem;
    __bf16* Bs = smem + 128 * 32;
    int tid  = threadIdx.x;
    int wv   = tid >> 6, lane = tid & 63;

    // ---- XCD swizzle ----
    int L   = blockIdx.x + gridDim.x * (blockIdx.y + gridDim.y * blockIdx.z);
    int xcd = L & 7, j = L >> 3;
    int ff  = fx * fy;
    int zw  = xcd / ff;
    int rr  = xcd % ff;
    int nxf = gridDim.x / fx;
    int bnw = (j % nxf) * fx + (rr % fx);
    int bmw = (j / nxf) * fy + (rr / fx);
    int bn  = bnw * 128, bm = bmw * 128;

    int wm   = (wv & 1) * 64, wn = (wv >> 1) * 64;
    int l16  = lane & 15, g16 = lane >> 4;

    int kc   = Kd / gridDim.z;
    int zoff = zw * kc;

    const __bf16* Ause = (bn >= asplit) ? A2 : A;

    const __bf16* ag0 = Ause + (size_t)(bm + (tid >> 2)) * Kd + zoff + (tid & 3) * 8;
    const __bf16* ag1 = ag0 + (size_t)64 * Kd;
    const __bf16* bg0 = Bt + (size_t)(bn + (tid >> 2)) * Kd + zoff + (tid & 3) * 8;
    const __bf16* bg1 = bg0 + (size_t)64 * Kd;
    __bf16* al0 = &As[tid * 8];
    __bf16* al1 = &As[2048 + tid * 8];
    __bf16* bl0 = &Bs[tid * 8];
    __bf16* bl1 = &Bs[2048 + tid * 8];

    floatx4 acc[4][4] = {};

    if (REG) {
        // register-prefetch pipeline
        bf16x8 pa0 = *(const bf16x8*)ag0;
        bf16x8 pa1 = *(const bf16x8*)ag1;
        bf16x8 pb0 = *(const bf16x8*)bg0;
        bf16x8 pb1 = *(const bf16x8*)bg1;
        for (int k0 = 0; k0 < kc; k0 += 32) {
            *(bf16x8*)al0 = pa0;
            *(bf16x8*)al1 = pa1;
            *(bf16x8*)bl0 = pb0;
            *(bf16x8*)bl1 = pb1;
            if (k0 + 32 < kc) {
                ag0 += 32; ag1 += 32; bg0 += 32; bg1 += 32;
                pa0 = *(const bf16x8*)ag0;
                pa1 = *(const bf16x8*)ag1;
                pb0 = *(const bf16x8*)bg0;
                pb1 = *(const bf16x8*)bg1;
            }
            __syncthreads();
            bf16x8 af[4], bfr[4];
#pragma unroll
            for (int i = 0; i < 4; ++i)
                af[i] = *(const bf16x8*)&As[(wm + i * 16 + l16) * 32 + g16 * 8];
#pragma unroll
            for (int jj = 0; jj < 4; ++jj)
                bfr[jj] = *(const bf16x8*)&Bs[(wn + jj * 16 + l16) * 32 + g16 * 8];
#pragma unroll
            for (int i = 0; i < 4; ++i)
#pragma unroll
                for (int jj = 0; jj < 4; ++jj)
                    acc[i][jj] = __builtin_amdgcn_mfma_f32_16x16x32_bf16(af[i], bfr[jj], acc[i][jj], 0, 0, 0);
            __syncthreads();
        }
    } else {
        // m97-style DMA staging
        for (int k0 = 0; k0 < kc; k0 += 32) {
            __syncthreads();
            load_lds16(ag0, al0); load_lds16(ag1, al1);
            load_lds16(bg0, bl0); load_lds16(bg1, bl1);
            ag0 += 32; ag1 += 32; bg0 += 32; bg1 += 32;
            __syncthreads();
            bf16x8 af[4], bfr[4];
#pragma unroll
            for (int i = 0; i < 4; ++i)
                af[i] = *(const bf16x8*)&As[(wm + i * 16 + l16) * 32 + g16 * 8];
#pragma unroll
            for (int jj = 0; jj < 4; ++jj)
                bfr[jj] = *(const bf16x8*)&Bs[(wn + jj * 16 + l16) * 32 + g16 * 8];
#pragma unroll
            for (int i = 0; i < 4; ++i)
#pragma unroll
                for (int jj = 0; jj < 4; ++jj)
                    acc[i][jj] = __builtin_amdgcn_mfma_f32_16x16x32_bf16(af[i], bfr[jj], acc[i][jj], 0, 0, 0);
        }
        __syncthreads();               // all waves done reading before epilogue reuse
    }

    __bf16* Cp = (zw == 0) ? cb : cbalt + (size_t)(zw - 1) * M * N;
    const float* bz = (zw == 0) ? bias : nullptr;

    // ---- coalesced epilogue via per-wave LDS transpose ----
    __bf16* eb = smem + wv * 2048;
    int erow = lane >> 2;
    int ecol = (lane & 3) * 16;
#pragma unroll
    for (int i = 0; i < 4; ++i) {
#pragma unroll
        for (int jj = 0; jj < 4; ++jj) {
            int col  = bn + wn + jj * 16 + l16;
            float sc = (col < split) ? scale0 : scale1;
            float bv = bz ? bz[col] : 0.f;
#pragma unroll
            for (int r = 0; r < 4; ++r) {
                float v = acc[i][jj][r] * sc + bv;
                if (RELU) v = fmaxf(v, 0.f);
                eb[(g16 * 4 + r) * 76 + jj * 16 + l16] = (__bf16)v;
            }
        }
        bf16x8 t0 = *(const bf16x8*)&eb[erow * 76 + ecol];
        bf16x8 t1 = *(const bf16x8*)&eb[erow * 76 + ecol + 8];
        size_t gb = (size_t)(bm + wm + i * 16 + erow) * N + bn + wn + ecol;
        *(bf16x8*)&Cp[gb]     = t0;
        *(bf16x8*)&Cp[gb + 8] = t1;
    }
}

// ===================================================== 256x256 8-phase GEMM
// R3-proven variant (measured best): 8 phases per 2-K-tile iteration, ONE
// closing barrier per phase (no opening barrier / lgkmcnt(0) — the compiler
// emits counted lgkmcnt between each ds_read and its first consuming MFMA,
// so waves skew within a phase and LDS reads of one wave overlap MFMAs of
// another). Counted vmcnt(4) at phases 4/8 only (never 0 in the main loop).
// XOR bank swizzle via pre-swizzled global source + swizzled ds_read
// (conflicts measured 0). Fragment caching: a_ per QM pair, b0_/b1_ once
// per K-tile. setprio(1) around MFMA clusters.
// Liveness (verified): every staged region's last LDS read is >=2 barriers
// before its stage issue; every read of freshly staged data sits behind a
// VM4/VM0 asm-clobber + barrier.
//
// V-fusion (R8, kept): for the QKV gemms, the V column range [vlo,vlo+1024)
// is written TRANSPOSED directly to vt ([bh][64 s][1024 t] layout) — each
// lane's acc[i][j][0..3] is 4 consecutive t at one s → one contiguous
// bf16x4 store. Removes the transpose_v dispatches and V round-trip.
//
// Split-K: blockIdx.y = z-slice; kc = Kd / gridDim.y; z>0 writes bf16
// partial slices (Calt + (z-1)*M*N), bias only on z==0; ln_kernel sums.

#define VM4 asm volatile("s_waitcnt vmcnt(4)" ::: "memory")
#define VM0 asm volatile("s_waitcnt vmcnt(0)" ::: "memory")

#define STG(GB, HROWS, LDST, TILE)                                             \
    do {                                                                       \
        load_lds16((GB) + (size_t)(HROWS) * Kd + (TILE) * 64, (LDST) + tid8);  \
        load_lds16((GB) + (size_t)((HROWS) + 128) * Kd + (TILE) * 64,          \
                   (LDST) + 4096 + tid8);                                      \
    } while (0)

#define RD_A(ABUF, QM)                                                         \
    _Pragma("unroll")                                                          \
    for (int i2 = 0; i2 < 4; ++i2) {                                           \
        int s_ = (QM) * 128 + wr64 + i2 * 16 + l16;                            \
        a_[i2][0] = *(const bf16x8*)&(ABUF)[s_ * 64 + pa0];                    \
        a_[i2][1] = *(const bf16x8*)&(ABUF)[s_ * 64 + pa1];                    \
    }

#define RD_B(BBUF, QN, BREG)                                                   \
    _Pragma("unroll")                                                          \
    for (int j2 = 0; j2 < 2; ++j2) {                                           \
        int s_ = (QN) * 128 + wc32 + j2 * 16 + l16;                            \
        BREG[j2][0] = *(const bf16x8*)&(BBUF)[s_ * 64 + pa0];                  \
        BREG[j2][1] = *(const bf16x8*)&(BBUF)[s_ * 64 + pa1];                  \
    }

#define CORE(QM, QN, BREG, STAGE, TAIL)                                         \
    {                                                                           \
        STAGE;                                                                  \
        __builtin_amdgcn_s_setprio(1);                                          \
        _Pragma("unroll")                                                       \
        for (int i2 = 0; i2 < 4; ++i2)                                          \
            _Pragma("unroll")                                                   \
            for (int j2 = 0; j2 < 2; ++j2) {                                    \
                acc[(QM) * 4 + i2][(QN) * 2 + j2] =                             \
                    __builtin_amdgcn_mfma_f32_16x16x32_bf16(                    \
                        a_[i2][0], BREG[j2][0],                                 \
                        acc[(QM) * 4 + i2][(QN) * 2 + j2], 0, 0, 0);            \
                acc[(QM) * 4 + i2][(QN) * 2 + j2] =                             \
                    __builtin_amdgcn_mfma_f32_16x16x32_bf16(                    \
                        a_[i2][1], BREG[j2][1],                                 \
                        acc[(QM) * 4 + i2][(QN) * 2 + j2], 0, 0, 0);            \
            }                                                                   \
        __builtin_amdgcn_s_setprio(0);                                          \
        TAIL;                                                                   \
        __builtin_amdgcn_s_barrier();                                           \
    }

template <int RELU>
__launch_bounds__(512, 2)
__global__ void gemm256(const __bf16* __restrict__ A, const __bf16* __restrict__ A2,
                        int asplit, const __bf16* __restrict__ Bt,
                        __bf16* __restrict__ C, __bf16* __restrict__ Calt,
                        const float* __restrict__ bias,
                        int M, int N, int Kd, float scale0, float scale1,
                        int split, int pw,
                        __bf16* __restrict__ vtp, int vlo) {
    __shared__ alignas(16) __bf16 smem[65536];   // 128 KiB
    __bf16* Alds0 = smem;
    __bf16* Alds1 = smem + 16384;
    __bf16* Blds0 = smem + 32768;
    __bf16* Blds1 = smem + 49152;

    int tid = threadIdx.x;
    int wv = tid >> 6, lane = tid & 63;
    int l16 = lane & 15, g16 = lane >> 4;
    int wr = wv >> 2, wc = wv & 3;          // 2M x 4N wave grid
    int wr64 = wr * 64, wc32 = wc * 32;
    int pa0 = (g16 ^ (l16 & 7)) * 8;        // swizzled unit for kk=0 (elements)
    int pa1 = pa0 ^ 32;                     // kk=1

    // XCD-aware mapping: each XCD gets a 4 x pw patch of 256^2 tiles.
    int L = blockIdx.x;
    int xcd = L & 7, jj = L >> 3;
    int bm = ((xcd >> 1) * 4 + jj / pw) * 256;
    int bn = ((xcd & 1) * pw + jj % pw) * 256;

    // split-K slice
    int z = blockIdx.y;
    int kc = Kd / gridDim.y;
    int zoff = z * kc;

    const __bf16* Ause = (bn >= asplit) ? A2 : A;
    int tid8 = tid * 8;
    int colOff = ((tid & 7) ^ ((tid >> 3) & 7)) * 8;   // inverse swizzle on src
    const __bf16* baseA = Ause + (size_t)(bm + (tid >> 3)) * Kd + zoff + colOff;
    const __bf16* baseB = Bt + (size_t)(bn + (tid >> 8) * 64 + ((tid >> 3) & 31)) * Kd + zoff + colOff;

    floatx4 acc[8][4] = {};
    bf16x8 a_[4][2], b0_[2][2], b1_[2][2];

    // prologue: tile0 complete (4 halves) + tile1 A-h0,B-h0
    STG(baseA, 0,  Alds0,        0);
    STG(baseB, 0,  Blds0,        0);
    STG(baseA, 64, Alds0 + 8192, 0);
    STG(baseB, 32, Blds0 + 8192, 0);
    STG(baseA, 0,  Alds1,        1);
    STG(baseB, 0,  Blds1,        1);
    VM4;                                    // tile0 landed; tile1 halves in flight
    __builtin_amdgcn_s_barrier();

    int niter = kc >> 7;                    // two 64-wide K-tiles per iteration
    for (int t = 0; t < niter - 1; ++t) {
        int tv = 2 * t + 1, tn0 = 2 * t + 2, tn1 = 2 * t + 3;
        RD_B(Blds0, 0, b0_); RD_A(Alds0, 0);
        CORE(0, 0, b0_, STG(baseA, 64, Alds1 + 8192, tv),  (void)0);
        RD_B(Blds0, 1, b1_);
        CORE(0, 1, b1_, STG(baseB, 32, Blds1 + 8192, tv),  (void)0);
        RD_A(Alds0, 1);
        CORE(1, 0, b0_, STG(baseA, 0,  Alds0,        tn0), (void)0);
        CORE(1, 1, b1_, STG(baseB, 0,  Blds0,        tn0), VM4);
        RD_B(Blds1, 0, b0_); RD_A(Alds1, 0);
        CORE(0, 0, b0_, STG(baseA, 64, Alds0 + 8192, tn0), (void)0);
        RD_B(Blds1, 1, b1_);
        CORE(0, 1, b1_, STG(baseB, 32, Blds0 + 8192, tn0), (void)0);
        RD_A(Alds1, 1);
        CORE(1, 0, b0_, STG(baseA, 0,  Alds1,        tn1), (void)0);
        CORE(1, 1, b1_, STG(baseB, 0,  Blds1,        tn1), VM4);
    }
    {   // final iteration: only tile v's second halves remain to stage
        int tv = (kc >> 6) - 1;
        RD_B(Blds0, 0, b0_); RD_A(Alds0, 0);
        CORE(0, 0, b0_, STG(baseA, 64, Alds1 + 8192, tv), (void)0);
        RD_B(Blds0, 1, b1_);
        CORE(0, 1, b1_, STG(baseB, 32, Blds1 + 8192, tv), (void)0);
        RD_A(Alds0, 1);
        CORE(1, 0, b0_, (void)0, (void)0);
        CORE(1, 1, b1_, (void)0, VM0);
        RD_B(Blds1, 0, b0_); RD_A(Alds1, 0);
        CORE(0, 0, b0_, (void)0, (void)0);
        RD_B(Blds1, 1, b1_);
        CORE(0, 1, b1_, (void)0, (void)0);
        RD_A(Alds1, 1);
        CORE(1, 0, b0_, (void)0, (void)0);
        CORE(1, 1, b1_, (void)0, (void)0);
    }

    __syncthreads();                        // full drain before smem reuse

    __bf16* Cp = (z == 0) ? C : Calt + (size_t)(z - 1) * M * N;
    const float* bz = (z == 0) ? bias : nullptr;

    float sc[4], bv[4];
#pragma unroll
    for (int j = 0; j < 4; ++j) {
        int col = bn + wc * 64 + j * 16 + l16;
        sc[j] = (col < split) ? scale0 : scale1;
        bv[j] = bz ? bz[col] : 0.f;
    }

    int c0 = bn + wc * 64;                  // wave's 64-col slice base
    if (vtp && c0 >= vlo && c0 < vlo + 1024) {
        // ---- V-fused transposed write: acc rows -> vt[bh][s][t] ----
        int hh = (c0 - vlo) >> 6;           // whole slice inside one head
#pragma unroll
        for (int i = 0; i < 8; ++i) {
            int rbase = bm + wr * 128 + i * 16 + g16 * 4;
            int bb = rbase >> 10, tt = rbase & 1023;
#pragma unroll
            for (int j = 0; j < 4; ++j) {
                bf16x4 ok;
#pragma unroll
                for (int r = 0; r < 4; ++r)
                    ok[r] = (__bf16)(acc[i][j][r] * sc[j] + bv[j]);
                int ss = j * 16 + l16;
                *(bf16x4*)&vtp[(((size_t)bb * 16 + hh) * 64 + ss) * 1024 + tt] = ok;
            }
        }
    } else {
        // ---- coalesced epilogue via per-wave LDS transpose ----
        __bf16* eb = smem + wv * 1216;      // 16 rows x 76 stride per wave
        int erow = lane >> 2;
        int ecol = (lane & 3) * 16;
#pragma unroll
        for (int i = 0; i < 8; ++i) {
#pragma unroll
            for (int j = 0; j < 4; ++j) {
#pragma unroll
                for (int r = 0; r < 4; ++r) {
                    float v = acc[i][j][r] * sc[j] + bv[j];
                    if (RELU) v = fmaxf(v, 0.f);
                    eb[(g16 * 4 + r) * 76 + j * 16 + l16] = (__bf16)v;
                }
            }
            bf16x8 t0 = *(const bf16x8*)&eb[erow * 76 + ecol];
            bf16x8 t1 = *(const bf16x8*)&eb[erow * 76 + ecol + 8];
            size_t gb = (size_t)(bm + wr * 128 + i * 16 + erow) * N + bn + wc * 64 + ecol;
            *(bf16x8*)&Cp[gb]     = t0;
            *(bf16x8*)&Cp[gb + 8] = t1;
        }
    }
}

// ------------------------------------------------------- flash attention
// TQ=128: two 64-row Q-subtiles per block share each staged K/V tile —
// half the staging/barriers per unit work vs TQ=64. S^T = K·Q^T (lane owns
// one q-row); O kept transposed (A=V^T, B=P); no-max exp2 softmax (scores
// bounded); XCD-local mapping; register-prefetch K/V double buffer.
// Q IN REGISTERS (this round): each wave only ever consumes 4 fixed Q
// fragments ((sub,kk) in {0,1}^2, row = wv*16+l16 lane-determined), so Q is
// loaded once from global into 4 bf16x8 regs — the 16 KB Qs LDS buffer and
// its staging are deleted. LDS 46->27 KB lifts occupancy 3->4 blocks/CU
// (VGPR ~85 < 128 keeps the 4-waves/SIMD cap) for this latency-chained
// kernel. All other schedule/arithmetic identical.
// Causal balance: qt2 complemented for the scheduler's second round so each
// CU's two blocks sum to constant work.
__launch_bounds__(256, 4)
__global__ void attn_kernel(const __bf16* __restrict__ qb, const __bf16* __restrict__ kb,
                            const __bf16* __restrict__ vt, int ldq, int ldk,
                            __bf16* __restrict__ out, int causal, int Tc) {
    constexpr int T = 1024;
    __shared__ alignas(16) __bf16 Ks[64 * 72];
    __shared__ alignas(16) __bf16 Vs[64 * 72];
    __shared__ alignas(16) __bf16 Ps[4][16 * 72];

    int tid = threadIdx.x;
    int wv = tid >> 6, lane = tid & 63;
    int l16 = lane & 15, g16 = lane >> 4;

    // XCD-local mapping over 512 blocks: all 8 q-tiles of a (b,h) pair share
    // an XCD; blocks L and L+256 get complementary qt2 (causal balance).
    int L = blockIdx.x;
    int xcd = L & 7, idx = L >> 3;
    int i3 = idx & 7;
    int qt2 = (idx & 32) ? (7 - i3) : i3;
    int pair = xcd + 8 * (idx >> 3);
    int h = pair & 15, b = pair >> 4;

    int r0 = tid >> 3, s8 = (tid & 7) * 8;
    int r1 = r0 + 32;

    // Q fragments in registers: exactly the values the old Qs LDS reads
    // produced — row = qt2*128 + sub*64 + wv*16 + l16, cols kk*32+g16*8.
    bf16x8 qf[2][2];
#pragma unroll
    for (int sub = 0; sub < 2; ++sub)
#pragma unroll
        for (int kk = 0; kk < 2; ++kk)
            qf[sub][kk] = *(const bf16x8*)(qb
                + (size_t)(b * T + qt2 * 128 + sub * 64 + wv * 16 + l16) * ldq
                + h * 64 + kk * 32 + g16 * 8);

    floatx4 oacc[2][4] = {};
    float li[2] = {0.f, 0.f};

    int ktend = causal ? (2 * qt2 + 2) : (Tc / 64);

    const __bf16* kbase = kb + (size_t)b * Tc * ldk + h * 64 + s8;
    const __bf16* vbase = vt + (size_t)(b * 16 + h) * 64 * Tc + s8;

    bf16x8 kc0 = *(const bf16x8*)(kbase + (size_t)r0 * ldk);
    bf16x8 kc1 = *(const bf16x8*)(kbase + (size_t)r1 * ldk);
    bf16x8 vc0 = *(const bf16x8*)(vbase + (size_t)r0 * Tc);
    bf16x8 vc1 = *(const bf16x8*)(vbase + (size_t)r1 * Tc);
    bf16x8 kn0, kn1, vn0, vn1;

    for (int kt = 0; kt < ktend; ++kt) {
        __syncthreads();
        *(bf16x8*)&Ks[r0 * 72 + s8] = kc0;
        *(bf16x8*)&Ks[r1 * 72 + s8] = kc1;
        *(bf16x8*)&Vs[r0 * 72 + s8] = vc0;
        *(bf16x8*)&Vs[r1 * 72 + s8] = vc1;
        if (kt + 1 < ktend) {
            const __bf16* kp = kbase + (size_t)(kt + 1) * 64 * ldk;
            const __bf16* vp = vbase + (size_t)(kt + 1) * 64;
            kn0 = *(const bf16x8*)(kp + (size_t)r0 * ldk);
            kn1 = *(const bf16x8*)(kp + (size_t)r1 * ldk);
            vn0 = *(const bf16x8*)(vp + (size_t)r0 * Tc);
            vn1 = *(const bf16x8*)(vp + (size_t)r1 * Tc);
        }
        __syncthreads();

#pragma unroll
        for (int sub = 0; sub < 2; ++sub) {
            if (causal && kt > 2 * qt2 + sub) continue;   // wave-uniform skip

            floatx4 sacc[4] = {};
#pragma unroll
            for (int kk = 0; kk < 2; ++kk) {
#pragma unroll
                for (int j = 0; j < 4; ++j) {
                    bf16x8 ak = *(const bf16x8*)&Ks[(j * 16 + l16) * 72 + kk * 32 + g16 * 8];
                    sacc[j] = __builtin_amdgcn_mfma_f32_16x16x32_bf16(ak, qf[sub][kk], sacc[j], 0, 0, 0);
                }
            }
            if (causal && kt == 2 * qt2 + sub) {
                int qloc = wv * 16 + l16;
#pragma unroll
                for (int j = 0; j < 4; ++j)
#pragma unroll
                    for (int r = 0; r < 4; ++r)
                        if (j * 16 + g16 * 4 + r > qloc) sacc[j][r] = -1e30f;
            }

#pragma unroll
            for (int j = 0; j < 4; ++j) {
                bf16x4 pk;
#pragma unroll
                for (int r = 0; r < 4; ++r) {
                    float p = __builtin_amdgcn_exp2f(sacc[j][r]);
                    li[sub] += p;
                    pk[r] = (__bf16)p;
                }
                *(bf16x4*)&Ps[wv][l16 * 72 + j * 16 + g16 * 4] = pk;
            }
#pragma unroll
            for (int kk = 0; kk < 2; ++kk) {
                bf16x8 bp = *(const bf16x8*)&Ps[wv][l16 * 72 + kk * 32 + g16 * 8];
#pragma unroll
                for (int j = 0; j < 4; ++j) {
                    bf16x8 av = *(const bf16x8*)&Vs[(j * 16 + l16) * 72 + kk * 32 + g16 * 8];
                    oacc[sub][j] = __builtin_amdgcn_mfma_f32_16x16x32_bf16(av, bp, oacc[sub][j], 0, 0, 0);
                }
            }
        }
        kc0 = kn0; kc1 = kn1; vc0 = vn0; vc1 = vn1;
    }

    li[0] += __shfl_xor(li[0], 16); li[0] += __shfl_xor(li[0], 32);
    li[1] += __shfl_xor(li[1], 16); li[1] += __shfl_xor(li[1], 32);

    // transpose O^T -> O through LDS (reuse Ks; per-wave slice, in-order)
    __syncthreads();
    int rw = lane >> 2, c4 = (lane & 3) * 16;
#pragma unroll
    for (int sub = 0; sub < 2; ++sub) {
        float inv = 1.f / li[sub];
#pragma unroll
        for (int j = 0; j < 4; ++j) {
            bf16x4 ok;
#pragma unroll
            for (int r = 0; r < 4; ++r) ok[r] = (__bf16)(oacc[sub][j][r] * inv);
            *(bf16x4*)&Ks[(wv * 16 + l16) * 72 + j * 16 + g16 * 4] = ok;
        }
        bf16x8 o0 = *(const bf16x8*)&Ks[(wv * 16 + rw) * 72 + c4];
        bf16x8 o1 = *(const bf16x8*)&Ks[(wv * 16 + rw) * 72 + c4 + 8];
        size_t ob = (size_t)(b * T + qt2 * 128 + sub * 64 + wv * 16 + rw) * EMB + h * 64 + c4;
        *(bf16x8*)&out[ob]     = o0;
        *(bf16x8*)&out[ob + 8] = o1;
    }
}

// --------------------------- residual + bf16 split-K partials + layernorm
// Residual chain in bf16 (R9, kept): ln2/ln3 read the bf16 y (x1b) as the
// residual base (exactly the value the gemm path consumes); ln2 updates x1b
// in place (per-thread read-before-write, no cross-thread overlap). Saves
// 48 MB of HBM traffic. RT = residual element type.
template <typename RT>
__launch_bounds__(256)
__global__ void ln_kernel(const RT* res,
                          const __bf16* __restrict__ pb, int np,
                          const float* __restrict__ g, const float* __restrict__ be,
                          float* outf, __bf16* outb) {
    __shared__ float red[8];
    int row = blockIdx.x, tid = threadIdx.x;
    size_t base = (size_t)row * EMB;
    float4 v;
    if constexpr (sizeof(RT) == 4) {
        v = ((const float4*)(res + base))[tid];
    } else {
        bf16x4 rv = *(const bf16x4*)(res + base + tid * 4);
        v.x = (float)rv[0]; v.y = (float)rv[1];
        v.z = (float)rv[2]; v.w = (float)rv[3];
    }
    for (int i = 0; i < np; ++i) {
        bf16x4 u = *(const bf16x4*)(pb + i * PSTRIDE + base + tid * 4);
        v.x += (float)u[0]; v.y += (float)u[1];
        v.z += (float)u[2]; v.w += (float)u[3];
    }
    float s  = v.x + v.y + v.z + v.w;
    float ss = v.x * v.x + v.y * v.y + v.z * v.z + v.w * v.w;
#pragma unroll
    for (int o = 1; o < 64; o <<= 1) { s += __shfl_xor(s, o); ss += __shfl_xor(ss, o); }
    if ((tid & 63) == 0) { red[(tid >> 6) * 2] = s; red[(tid >> 6) * 2 + 1] = ss; }
    __syncthreads();
    s  = red[0] + red[2] + red[4] + red[6];
    ss = red[1] + red[3] + red[5] + red[7];
    float mu  = s * (1.0f / 1024.0f);
    float var = ss * (1.0f / 1024.0f) - mu * mu;
    float rs  = rsqrtf(var + 1e-5f);
    float4 gg = ((const float4*)g)[tid];
    float4 bb = ((const float4*)be)[tid];
    float4 y;
    y.x = (v.x - mu) * rs * gg.x + bb.x;
    y.y = (v.y - mu) * rs * gg.y + bb.y;
    y.z = (v.z - mu) * rs * gg.z + bb.z;
    y.w = (v.w - mu) * rs * gg.w + bb.w;
    if (outf) ((float4*)(outf + base))[tid] = y;
    if (outb) {
        bf16x4 o;
        o[0] = (__bf16)y.x; o[1] = (__bf16)y.y; o[2] = (__bf16)y.z; o[3] = (__bf16)y.w;
        *(bf16x4*)(outb + base + tid * 4) = o;
    }
}

// ---------------------------------------------------------------- launch
extern "C" void kernel_launch(void* const* d_in, const int* in_sizes, int n_in,
                              void* d_out, int out_size, void* d_ws, size_t ws_size,
                              hipStream_t stream) {
    const float* x     = (const float*)d_in[0];
    const float* ctx   = (const float*)d_in[1];
    const float* sa_wq = (const float*)d_in[2];
    const float* sa_wk = (const float*)d_in[3];
    const float* sa_wv = (const float*)d_in[4];
    const float* sa_wo = (const float*)d_in[5];
    const float* sa_bo = (const float*)d_in[6];
    const float* ca_wq = (const float*)d_in[7];
    const float* ca_wk = (const float*)d_in[8];
    const float* ca_wv = (const float*)d_in[9];
    const float* ca_wo = (const float*)d_in[10];
    const float* ca_bo = (const float*)d_in[11];
    const float* n1_g = (const float*)d_in[12];
    const float* n1_b = (const float*)d_in[13];
    const float* n2_g = (const float*)d_in[14];
    const float* n2_b = (const float*)d_in[15];
    const float* n3_g = (const float*)d_in[16];
    const float* n3_b = (const float*)d_in[17];
    const float* ff_w1 = (const float*)d_in[18];
    const float* ff_b1 = (const float*)d_in[19];
    const float* ff_w2 = (const float*)d_in[20];
    const float* ff_b2 = (const float*)d_in[21];

    size_t off = 0;
    auto alloc = [&](size_t bytes) {
        void* p = (char*)d_ws + off;
        off += (bytes + 255) & ~(size_t)255;
        return p;
    };
    __bf16* w_sa_qkvT = (__bf16*)alloc((size_t)3 * EMB * EMB * 2);  // [q;k;v]
    __bf16* w_sa_oT   = (__bf16*)alloc((size_t)EMB * EMB * 2);
    __bf16* w_ca_kvqT = (__bf16*)alloc((size_t)3 * EMB * EMB * 2);  // [k;v;q]
    __bf16* w_ca_oT   = (__bf16*)alloc((size_t)EMB * EMB * 2);
    __bf16* w1T       = (__bf16*)alloc((size_t)HIDN * EMB * 2);
    __bf16* w2T       = (__bf16*)alloc((size_t)EMB * HIDN * 2);
    __bf16* xb        = (__bf16*)alloc((size_t)MROWS * EMB * 2);     // 8 MB
    __bf16* qkv       = (__bf16*)alloc((size_t)MROWS * 3 * EMB * 2); // 24 MB, adjacent
    __bf16* ao        = (__bf16*)alloc((size_t)MROWS * EMB * 2);     // 8 MB
    __bf16* hid       = (__bf16*)alloc((size_t)MROWS * HIDN * 2);    // 32 MB
    __bf16* x1b       = (__bf16*)alloc((size_t)MROWS * EMB * 2);     // 8 MB
    __bf16* vt        = (__bf16*)alloc((size_t)MROWS * EMB * 2);     // 8 MB
    __bf16* ctxb      = (__bf16*)alloc((size_t)MROWS * EMB * 2);     // 8 MB

    __bf16* qkvc = qkv;              // CA merged output [k|v|q] (reuses qkv)
    __bf16* pbo  = qkv;              // attn-proj split-K partials (2x8MB)
    __bf16* pbf  = xb;               // ff2 partials (4x8MB over xb+qkv)
    // residual chain lives in x1b (bf16): ln1 y -> x1b; ln2 reads x1b,
    // updates in place; ln3 reads x1b. No fp32 res buffers.

    // Q pre-scale: (1024^-0.25)^2 * log2(e) — softmax runs in exp2 domain
    const float QSC = 0.04508422002778011f;
    const int   BIG = 1 << 30;
    dim3 tb(32, 8);

    // ---- all weight transposes in ONE dispatch (16 jobs) ----
    TJobs tj;
    tj.s[0] = sa_wq; tj.d[0] = w_sa_qkvT;                          tj.sld[0] = EMB;  tj.dld[0] = EMB;
    tj.s[1] = sa_wk; tj.d[1] = w_sa_qkvT + (size_t)EMB * EMB;      tj.sld[1] = EMB;  tj.dld[1] = EMB;
    tj.s[2] = sa_wv; tj.d[2] = w_sa_qkvT + (size_t)2 * EMB * EMB;  tj.sld[2] = EMB;  tj.dld[2] = EMB;
    tj.s[3] = sa_wo; tj.d[3] = w_sa_oT;                            tj.sld[3] = EMB;  tj.dld[3] = EMB;
    tj.s[4] = ca_wk; tj.d[4] = w_ca_kvqT;                          tj.sld[4] = EMB;  tj.dld[4] = EMB;
    tj.s[5] = ca_wv; tj.d[5] = w_ca_kvqT + (size_t)EMB * EMB;      tj.sld[5] = EMB;  tj.dld[5] = EMB;
    tj.s[6] = ca_wq; tj.d[6] = w_ca_kvqT + (size_t)2 * EMB * EMB;  tj.sld[6] = EMB;  tj.dld[6] = EMB;
    tj.s[7] = ca_wo; tj.d[7] = w_ca_oT;                            tj.sld[7] = EMB;  tj.dld[7] = EMB;
    for (int c = 0; c < 4; ++c) {   // ff_w1 [1024][4096] -> w1T [4096][1024]
        tj.s[8 + c] = ff_w1 + (size_t)c * 1024;
        tj.d[8 + c] = w1T + (size_t)c * 1024 * 1024;
        tj.sld[8 + c] = HIDN; tj.dld[8 + c] = EMB;
    }
    for (int c = 0; c < 4; ++c) {   // ff_w2 [4096][1024] -> w2T [1024][4096]
        tj.s[12 + c] = ff_w2 + (size_t)c * 1024 * 1024;
        tj.d[12 + c] = w2T + (size_t)c * 1024;
        tj.sld[12 + c] = EMB; tj.dld[12 + c] = HIDN;
    }
    transpose_cast16_kernel<<<dim3(32, 32, 16), tb, 0, stream>>>(tj);

    // ---- both activation casts in one dispatch ----
    cast2_bf16_kernel<<<8192, 256, 0, stream>>>(x, ctx, xb, ctxb, MROWS * EMB);

    // ---- self attention ----
    gemm256<0><<<192, 512, 0, stream>>>(xb, xb, BIG, w_sa_qkvT,
        qkv, nullptr, nullptr, MROWS, 3 * EMB, EMB, QSC, 1.f, 1024, 6, vt, 2048);
    attn_kernel<<<512, 256, 0, stream>>>(qkv, qkv + EMB, vt, 3 * EMB, 3 * EMB, ao, 1, 1024);
    gemm_bt<0, 1><<<dim3(8, 32, 2), 256, 0, stream>>>(ao, ao, BIG, w_sa_oT,
        pbo, pbo + PSTRIDE, sa_bo, MROWS, EMB, EMB, 1.f, 1.f, 0, 2, 2);
    ln_kernel<float><<<4096, 256, 0, stream>>>(x, pbo, 2, n1_g, n1_b, nullptr, x1b);

    // ---- cross attention ----
    gemm256<0><<<192, 512, 0, stream>>>(ctxb, x1b, 2048, w_ca_kvqT,
        qkvc, nullptr, nullptr, MROWS, 3 * EMB, EMB, 1.f, QSC, 2048, 6, vt, 1024);
    attn_kernel<<<512, 256, 0, stream>>>(qkvc + 2 * EMB, qkvc, vt, 3 * EMB, 3 * EMB, ao, 0, 1024);
    gemm_bt<0, 1><<<dim3(8, 32, 2), 256, 0, stream>>>(ao, ao, BIG, w_ca_oT,
        pbo, pbo + PSTRIDE, ca_bo, MROWS, EMB, EMB, 1.f, 1.f, 0, 2, 2);
    ln_kernel<__bf16><<<4096, 256, 0, stream>>>(x1b, pbo, 2, n2_g, n2_b, nullptr, x1b);

    // ---- FFN ----
    gemm256<1><<<256, 512, 0, stream>>>(x1b, x1b, BIG, w1T,
        hid, nullptr, ff_b1, MROWS, HIDN, EMB, 1.f, 1.f, 0, 8, nullptr, BIG);
    gemm256<0><<<dim3(64, 4), 512, 0, stream>>>(hid, hid, BIG, w2T,
        pbf, pbf + PSTRIDE, ff_b2, MROWS, EMB, HIDN, 1.f, 1.f, 0, 2, nullptr, BIG);
    ln_kernel<__bf16><<<4096, 256, 0, stream>>>(x1b, pbf, 4, n3_g, n3_b, (float*)d_out, nullptr);
}

// Round 11
// 418.724 us; speedup vs baseline: 1.0320x; 1.0320x over previous
//
#include <hip/hip_runtime.h>

typedef __bf16 bf16x8 __attribute__((ext_vector_type(8)));
typedef __bf16 bf16x4 __attribute__((ext_vector_type(4)));
typedef float floatx4 __attribute__((ext_vector_type(4)));

#define EMB 1024
#define MROWS 4096
#define HIDN 4096
#define PSTRIDE ((size_t)MROWS * EMB)   // partial-slice stride (elements)

// ---------------------------------------------------------------- helpers
__device__ __forceinline__ void load_lds16(const __bf16* g, __bf16* l) {
    __builtin_amdgcn_global_load_lds(
        (const __attribute__((address_space(1))) void*)g,
        (__attribute__((address_space(3))) void*)l, 16, 0, 0);
}

// ----------------------- batched fp32->bf16 transposes (16 jobs, 1 dispatch)
struct TJobs { const float* s[16]; __bf16* d[16]; int sld[16]; int dld[16]; };
__global__ void transpose_cast16_kernel(TJobs a) {
    __shared__ float tile[32][33];
    int jz = blockIdx.z;
    const float* in = a.s[jz];
    __bf16* out = a.d[jz];
    int sld = a.sld[jz], dld = a.dld[jz];
    int tx = threadIdx.x, ty = threadIdx.y;
    int c0 = blockIdx.x * 32, r0 = blockIdx.y * 32;
#pragma unroll
    for (int i = 0; i < 32; i += 8)
        tile[ty + i][tx] = in[(size_t)(r0 + ty + i) * sld + c0 + tx];
    __syncthreads();
#pragma unroll
    for (int i = 0; i < 32; i += 8)
        out[(size_t)(c0 + ty + i) * dld + r0 + tx] = (__bf16)tile[tx][ty + i];
}

// ------------------------------------ fp32 -> bf16 cast, two tensors/launch
__global__ void cast2_bf16_kernel(const float* __restrict__ a,
                                  const float* __restrict__ b,
                                  __bf16* __restrict__ oa,
                                  __bf16* __restrict__ ob, int n) {
    int i = (blockIdx.x * 256 + threadIdx.x) * 4;
    const float* in = a;
    __bf16* out = oa;
    if (i >= n) { i -= n; in = b; out = ob; }
    float4 v = *(const float4*)(in + i);
    bf16x4 o;
    o[0] = (__bf16)v.x; o[1] = (__bf16)v.y; o[2] = (__bf16)v.z; o[3] = (__bf16)v.w;
    *(bf16x4*)(out + i) = o;
}

// ------------------------------------------------------------- GEMM (NT)
// 128x128-tile kernel for split-K short-K GEMMs (attn proj): REG=1
// register-prefetch path. Proven 13us/dispatch at z=2 (R3 dataflow).
template <int RELU, int REG>
__launch_bounds__(256, 4)
__global__ void gemm_bt(const __bf16* __restrict__ A, const __bf16* __restrict__ A2,
                        int asplit, const __bf16* __restrict__ Bt,
                        __bf16* __restrict__ cb, __bf16* __restrict__ cbalt,
                        const float* __restrict__ bias,
                        int M, int N, int Kd, float scale0, float scale1,
                        int split, int fx, int fy) {
    __shared__ alignas(16) __bf16 smem[2 * 128 * 32];
    __bf16* As = smem;
    __bf16* Bs = smem + 128 * 32;
    int tid  = threadIdx.x;
    int wv   = tid >> 6, lane = tid & 63;

    // ---- XCD swizzle ----
    int L   = blockIdx.x + gridDim.x * (blockIdx.y + gridDim.y * blockIdx.z);
    int xcd = L & 7, j = L >> 3;
    int ff  = fx * fy;
    int zw  = xcd / ff;
    int rr  = xcd % ff;
    int nxf = gridDim.x / fx;
    int bnw = (j % nxf) * fx + (rr % fx);
    int bmw = (j / nxf) * fy + (rr / fx);
    int bn  = bnw * 128, bm = bmw * 128;

    int wm   = (wv & 1) * 64, wn = (wv >> 1) * 64;
    int l16  = lane & 15, g16 = lane >> 4;

    int kc   = Kd / gridDim.z;
    int zoff = zw * kc;

    const __bf16* Ause = (bn >= asplit) ? A2 : A;

    const __bf16* ag0 = Ause + (size_t)(bm + (tid >> 2)) * Kd + zoff + (tid & 3) * 8;
    const __bf16* ag1 = ag0 + (size_t)64 * Kd;
    const __bf16* bg0 = Bt + (size_t)(bn + (tid >> 2)) * Kd + zoff + (tid & 3) * 8;
    const __bf16* bg1 = bg0 + (size_t)64 * Kd;
    __bf16* al0 = &As[tid * 8];
    __bf16* al1 = &As[2048 + tid * 8];
    __bf16* bl0 = &Bs[tid * 8];
    __bf16* bl1 = &Bs[2048 + tid * 8];

    floatx4 acc[4][4] = {};

    if (REG) {
        // register-prefetch pipeline
        bf16x8 pa0 = *(const bf16x8*)ag0;
        bf16x8 pa1 = *(const bf16x8*)ag1;
        bf16x8 pb0 = *(const bf16x8*)bg0;
        bf16x8 pb1 = *(const bf16x8*)bg1;
        for (int k0 = 0; k0 < kc; k0 += 32) {
            *(bf16x8*)al0 = pa0;
            *(bf16x8*)al1 = pa1;
            *(bf16x8*)bl0 = pb0;
            *(bf16x8*)bl1 = pb1;
            if (k0 + 32 < kc) {
                ag0 += 32; ag1 += 32; bg0 += 32; bg1 += 32;
                pa0 = *(const bf16x8*)ag0;
                pa1 = *(const bf16x8*)ag1;
                pb0 = *(const bf16x8*)bg0;
                pb1 = *(const bf16x8*)bg1;
            }
            __syncthreads();
            bf16x8 af[4], bfr[4];
#pragma unroll
            for (int i = 0; i < 4; ++i)
                af[i] = *(const bf16x8*)&As[(wm + i * 16 + l16) * 32 + g16 * 8];
#pragma unroll
            for (int jj = 0; jj < 4; ++jj)
                bfr[jj] = *(const bf16x8*)&Bs[(wn + jj * 16 + l16) * 32 + g16 * 8];
#pragma unroll
            for (int i = 0; i < 4; ++i)
#pragma unroll
                for (int jj = 0; jj < 4; ++jj)
                    acc[i][jj] = __builtin_amdgcn_mfma_f32_16x16x32_bf16(af[i], bfr[jj], acc[i][jj], 0, 0, 0);
            __syncthreads();
        }
    } else {
        // m97-style DMA staging
        for (int k0 = 0; k0 < kc; k0 += 32) {
            __syncthreads();
            load_lds16(ag0, al0); load_lds16(ag1, al1);
            load_lds16(bg0, bl0); load_lds16(bg1, bl1);
            ag0 += 32; ag1 += 32; bg0 += 32; bg1 += 32;
            __syncthreads();
            bf16x8 af[4], bfr[4];
#pragma unroll
            for (int i = 0; i < 4; ++i)
                af[i] = *(const bf16x8*)&As[(wm + i * 16 + l16) * 32 + g16 * 8];
#pragma unroll
            for (int jj = 0; jj < 4; ++jj)
                bfr[jj] = *(const bf16x8*)&Bs[(wn + jj * 16 + l16) * 32 + g16 * 8];
#pragma unroll
            for (int i = 0; i < 4; ++i)
#pragma unroll
                for (int jj = 0; jj < 4; ++jj)
                    acc[i][jj] = __builtin_amdgcn_mfma_f32_16x16x32_bf16(af[i], bfr[jj], acc[i][jj], 0, 0, 0);
        }
        __syncthreads();               // all waves done reading before epilogue reuse
    }

    __bf16* Cp = (zw == 0) ? cb : cbalt + (size_t)(zw - 1) * M * N;
    const float* bz = (zw == 0) ? bias : nullptr;

    // ---- coalesced epilogue via per-wave LDS transpose ----
    __bf16* eb = smem + wv * 2048;
    int erow = lane >> 2;
    int ecol = (lane & 3) * 16;
#pragma unroll
    for (int i = 0; i < 4; ++i) {
#pragma unroll
        for (int jj = 0; jj < 4; ++jj) {
            int col  = bn + wn + jj * 16 + l16;
            float sc = (col < split) ? scale0 : scale1;
            float bv = bz ? bz[col] : 0.f;
#pragma unroll
            for (int r = 0; r < 4; ++r) {
                float v = acc[i][jj][r] * sc + bv;
                if (RELU) v = fmaxf(v, 0.f);
                eb[(g16 * 4 + r) * 76 + jj * 16 + l16] = (__bf16)v;
            }
        }
        bf16x8 t0 = *(const bf16x8*)&eb[erow * 76 + ecol];
        bf16x8 t1 = *(const bf16x8*)&eb[erow * 76 + ecol + 8];
        size_t gb = (size_t)(bm + wm + i * 16 + erow) * N + bn + wn + ecol;
        *(bf16x8*)&Cp[gb]     = t0;
        *(bf16x8*)&Cp[gb + 8] = t1;
    }
}

// ===================================================== 256x256 8-phase GEMM
// R3-proven variant (measured best): 8 phases per 2-K-tile iteration, ONE
// closing barrier per phase (no opening barrier / lgkmcnt(0) — the compiler
// emits counted lgkmcnt between each ds_read and its first consuming MFMA,
// so waves skew within a phase and LDS reads of one wave overlap MFMAs of
// another). Counted vmcnt(4) at phases 4/8 only (never 0 in the main loop).
// XOR bank swizzle via pre-swizzled global source + swizzled ds_read
// (conflicts measured 0). Fragment caching: a_ per QM pair, b0_/b1_ once
// per K-tile. setprio(1) around MFMA clusters.
// Liveness (verified): every staged region's last LDS read is >=2 barriers
// before its stage issue; every read of freshly staged data sits behind a
// VM4/VM0 asm-clobber + barrier.
//
// V-fusion (R8, kept): for the QKV gemms, the V column range [vlo,vlo+1024)
// is written TRANSPOSED directly to vt ([bh][64 s][1024 t] layout) — each
// lane's acc[i][j][0..3] is 4 consecutive t at one s → one contiguous
// bf16x4 store. Removes the transpose_v dispatches and V round-trip.
//
// Split-K: blockIdx.y = z-slice; kc = Kd / gridDim.y; z>0 writes bf16
// partial slices (Calt + (z-1)*M*N), bias only on z==0; ln_kernel sums.

#define VM4 asm volatile("s_waitcnt vmcnt(4)" ::: "memory")
#define VM0 asm volatile("s_waitcnt vmcnt(0)" ::: "memory")

#define STG(GB, HROWS, LDST, TILE)                                             \
    do {                                                                       \
        load_lds16((GB) + (size_t)(HROWS) * Kd + (TILE) * 64, (LDST) + tid8);  \
        load_lds16((GB) + (size_t)((HROWS) + 128) * Kd + (TILE) * 64,          \
                   (LDST) + 4096 + tid8);                                      \
    } while (0)

#define RD_A(ABUF, QM)                                                         \
    _Pragma("unroll")                                                          \
    for (int i2 = 0; i2 < 4; ++i2) {                                           \
        int s_ = (QM) * 128 + wr64 + i2 * 16 + l16;                            \
        a_[i2][0] = *(const bf16x8*)&(ABUF)[s_ * 64 + pa0];                    \
        a_[i2][1] = *(const bf16x8*)&(ABUF)[s_ * 64 + pa1];                    \
    }

#define RD_B(BBUF, QN, BREG)                                                   \
    _Pragma("unroll")                                                          \
    for (int j2 = 0; j2 < 2; ++j2) {                                           \
        int s_ = (QN) * 128 + wc32 + j2 * 16 + l16;                            \
        BREG[j2][0] = *(const bf16x8*)&(BBUF)[s_ * 64 + pa0];                  \
        BREG[j2][1] = *(const bf16x8*)&(BBUF)[s_ * 64 + pa1];                  \
    }

#define CORE(QM, QN, BREG, STAGE, TAIL)                                         \
    {                                                                           \
        STAGE;                                                                  \
        __builtin_amdgcn_s_setprio(1);                                          \
        _Pragma("unroll")                                                       \
        for (int i2 = 0; i2 < 4; ++i2)                                          \
            _Pragma("unroll")                                                   \
            for (int j2 = 0; j2 < 2; ++j2) {                                    \
                acc[(QM) * 4 + i2][(QN) * 2 + j2] =                             \
                    __builtin_amdgcn_mfma_f32_16x16x32_bf16(                    \
                        a_[i2][0], BREG[j2][0],                                 \
                        acc[(QM) * 4 + i2][(QN) * 2 + j2], 0, 0, 0);            \
                acc[(QM) * 4 + i2][(QN) * 2 + j2] =                             \
                    __builtin_amdgcn_mfma_f32_16x16x32_bf16(                    \
                        a_[i2][1], BREG[j2][1],                                 \
                        acc[(QM) * 4 + i2][(QN) * 2 + j2], 0, 0, 0);            \
            }                                                                   \
        __builtin_amdgcn_s_setprio(0);                                          \
        TAIL;                                                                   \
        __builtin_amdgcn_s_barrier();                                           \
    }

template <int RELU>
__launch_bounds__(512, 2)
__global__ void gemm256(const __bf16* __restrict__ A, const __bf16* __restrict__ A2,
                        int asplit, const __bf16* __restrict__ Bt,
                        __bf16* __restrict__ C, __bf16* __restrict__ Calt,
                        const float* __restrict__ bias,
                        int M, int N, int Kd, float scale0, float scale1,
                        int split, int pw,
                        __bf16* __restrict__ vtp, int vlo) {
    __shared__ alignas(16) __bf16 smem[65536];   // 128 KiB
    __bf16* Alds0 = smem;
    __bf16* Alds1 = smem + 16384;
    __bf16* Blds0 = smem + 32768;
    __bf16* Blds1 = smem + 49152;

    int tid = threadIdx.x;
    int wv = tid >> 6, lane = tid & 63;
    int l16 = lane & 15, g16 = lane >> 4;
    int wr = wv >> 2, wc = wv & 3;          // 2M x 4N wave grid
    int wr64 = wr * 64, wc32 = wc * 32;
    int pa0 = (g16 ^ (l16 & 7)) * 8;        // swizzled unit for kk=0 (elements)
    int pa1 = pa0 ^ 32;                     // kk=1

    // XCD-aware mapping: each XCD gets a 4 x pw patch of 256^2 tiles.
    int L = blockIdx.x;
    int xcd = L & 7, jj = L >> 3;
    int bm = ((xcd >> 1) * 4 + jj / pw) * 256;
    int bn = ((xcd & 1) * pw + jj % pw) * 256;

    // split-K slice
    int z = blockIdx.y;
    int kc = Kd / gridDim.y;
    int zoff = z * kc;

    const __bf16* Ause = (bn >= asplit) ? A2 : A;
    int tid8 = tid * 8;
    int colOff = ((tid & 7) ^ ((tid >> 3) & 7)) * 8;   // inverse swizzle on src
    const __bf16* baseA = Ause + (size_t)(bm + (tid >> 3)) * Kd + zoff + colOff;
    const __bf16* baseB = Bt + (size_t)(bn + (tid >> 8) * 64 + ((tid >> 3) & 31)) * Kd + zoff + colOff;

    floatx4 acc[8][4] = {};
    bf16x8 a_[4][2], b0_[2][2], b1_[2][2];

    // prologue: tile0 complete (4 halves) + tile1 A-h0,B-h0
    STG(baseA, 0,  Alds0,        0);
    STG(baseB, 0,  Blds0,        0);
    STG(baseA, 64, Alds0 + 8192, 0);
    STG(baseB, 32, Blds0 + 8192, 0);
    STG(baseA, 0,  Alds1,        1);
    STG(baseB, 0,  Blds1,        1);
    VM4;                                    // tile0 landed; tile1 halves in flight
    __builtin_amdgcn_s_barrier();

    int niter = kc >> 7;                    // two 64-wide K-tiles per iteration
    for (int t = 0; t < niter - 1; ++t) {
        int tv = 2 * t + 1, tn0 = 2 * t + 2, tn1 = 2 * t + 3;
        RD_B(Blds0, 0, b0_); RD_A(Alds0, 0);
        CORE(0, 0, b0_, STG(baseA, 64, Alds1 + 8192, tv),  (void)0);
        RD_B(Blds0, 1, b1_);
        CORE(0, 1, b1_, STG(baseB, 32, Blds1 + 8192, tv),  (void)0);
        RD_A(Alds0, 1);
        CORE(1, 0, b0_, STG(baseA, 0,  Alds0,        tn0), (void)0);
        CORE(1, 1, b1_, STG(baseB, 0,  Blds0,        tn0), VM4);
        RD_B(Blds1, 0, b0_); RD_A(Alds1, 0);
        CORE(0, 0, b0_, STG(baseA, 64, Alds0 + 8192, tn0), (void)0);
        RD_B(Blds1, 1, b1_);
        CORE(0, 1, b1_, STG(baseB, 32, Blds0 + 8192, tn0), (void)0);
        RD_A(Alds1, 1);
        CORE(1, 0, b0_, STG(baseA, 0,  Alds1,        tn1), (void)0);
        CORE(1, 1, b1_, STG(baseB, 0,  Blds1,        tn1), VM4);
    }
    {   // final iteration: only tile v's second halves remain to stage
        int tv = (kc >> 6) - 1;
        RD_B(Blds0, 0, b0_); RD_A(Alds0, 0);
        CORE(0, 0, b0_, STG(baseA, 64, Alds1 + 8192, tv), (void)0);
        RD_B(Blds0, 1, b1_);
        CORE(0, 1, b1_, STG(baseB, 32, Blds1 + 8192, tv), (void)0);
        RD_A(Alds0, 1);
        CORE(1, 0, b0_, (void)0, (void)0);
        CORE(1, 1, b1_, (void)0, VM0);
        RD_B(Blds1, 0, b0_); RD_A(Alds1, 0);
        CORE(0, 0, b0_, (void)0, (void)0);
        RD_B(Blds1, 1, b1_);
        CORE(0, 1, b1_, (void)0, (void)0);
        RD_A(Alds1, 1);
        CORE(1, 0, b0_, (void)0, (void)0);
        CORE(1, 1, b1_, (void)0, (void)0);
    }

    __syncthreads();                        // full drain before smem reuse

    __bf16* Cp = (z == 0) ? C : Calt + (size_t)(z - 1) * M * N;
    const float* bz = (z == 0) ? bias : nullptr;

    float sc[4], bv[4];
#pragma unroll
    for (int j = 0; j < 4; ++j) {
        int col = bn + wc * 64 + j * 16 + l16;
        sc[j] = (col < split) ? scale0 : scale1;
        bv[j] = bz ? bz[col] : 0.f;
    }

    int c0 = bn + wc * 64;                  // wave's 64-col slice base
    if (vtp && c0 >= vlo && c0 < vlo + 1024) {
        // ---- V-fused transposed write: acc rows -> vt[bh][s][t] ----
        int hh = (c0 - vlo) >> 6;           // whole slice inside one head
#pragma unroll
        for (int i = 0; i < 8; ++i) {
            int rbase = bm + wr * 128 + i * 16 + g16 * 4;
            int bb = rbase >> 10, tt = rbase & 1023;
#pragma unroll
            for (int j = 0; j < 4; ++j) {
                bf16x4 ok;
#pragma unroll
                for (int r = 0; r < 4; ++r)
                    ok[r] = (__bf16)(acc[i][j][r] * sc[j] + bv[j]);
                int ss = j * 16 + l16;
                *(bf16x4*)&vtp[(((size_t)bb * 16 + hh) * 64 + ss) * 1024 + tt] = ok;
            }
        }
    } else {
        // ---- coalesced epilogue via per-wave LDS transpose ----
        __bf16* eb = smem + wv * 1216;      // 16 rows x 76 stride per wave
        int erow = lane >> 2;
        int ecol = (lane & 3) * 16;
#pragma unroll
        for (int i = 0; i < 8; ++i) {
#pragma unroll
            for (int j = 0; j < 4; ++j) {
#pragma unroll
                for (int r = 0; r < 4; ++r) {
                    float v = acc[i][j][r] * sc[j] + bv[j];
                    if (RELU) v = fmaxf(v, 0.f);
                    eb[(g16 * 4 + r) * 76 + j * 16 + l16] = (__bf16)v;
                }
            }
            bf16x8 t0 = *(const bf16x8*)&eb[erow * 76 + ecol];
            bf16x8 t1 = *(const bf16x8*)&eb[erow * 76 + ecol + 8];
            size_t gb = (size_t)(bm + wr * 128 + i * 16 + erow) * N + bn + wc * 64 + ecol;
            *(bf16x8*)&Cp[gb]     = t0;
            *(bf16x8*)&Cp[gb + 8] = t1;
        }
    }
}

// ------------------------------------------------------- flash attention
// R9-proven version (Q staged in LDS, 3 blocks/CU). R10's Q-in-registers
// variant REGRESSED (+3.4us) — occupancy was not the lever; reverted.
// TQ=128: two 64-row Q-subtiles per block share each staged K/V tile —
// half the staging/barriers per unit work vs TQ=64. S^T = K·Q^T (lane owns
// one q-row); O kept transposed (A=V^T, B=P); no-max exp2 softmax (scores
// bounded); XCD-local mapping; register-prefetch K/V double buffer.
// Causal balance: qt2 complemented for the scheduler's second round so each
// CU's two blocks sum to constant work.
__launch_bounds__(256, 3)
__global__ void attn_kernel(const __bf16* __restrict__ qb, const __bf16* __restrict__ kb,
                            const __bf16* __restrict__ vt, int ldq, int ldk,
                            __bf16* __restrict__ out, int causal, int Tc) {
    constexpr int T = 1024;
    __shared__ alignas(16) __bf16 Qs[128 * 72];
    __shared__ alignas(16) __bf16 Ks[64 * 72];
    __shared__ alignas(16) __bf16 Vs[64 * 72];
    __shared__ alignas(16) __bf16 Ps[4][16 * 72];

    int tid = threadIdx.x;
    int wv = tid >> 6, lane = tid & 63;
    int l16 = lane & 15, g16 = lane >> 4;

    // XCD-local mapping over 512 blocks: all 8 q-tiles of a (b,h) pair share
    // an XCD; blocks L and L+256 get complementary qt2 (causal balance).
    int L = blockIdx.x;
    int xcd = L & 7, idx = L >> 3;
    int i3 = idx & 7;
    int qt2 = (idx & 32) ? (7 - i3) : i3;
    int pair = xcd + 8 * (idx >> 3);
    int h = pair & 15, b = pair >> 4;

    int r0 = tid >> 3, s8 = (tid & 7) * 8;
    int r1 = r0 + 32;

    // stage Q tile: 128 rows x 64 dims (padded stride 72)
#pragma unroll
    for (int p = 0; p < 4; ++p) {
        int row = r0 + p * 32;
        bf16x8 qv = *(const bf16x8*)(qb + (size_t)(b * T + qt2 * 128 + row) * ldq + h * 64 + s8);
        *(bf16x8*)&Qs[row * 72 + s8] = qv;
    }

    floatx4 oacc[2][4] = {};
    float li[2] = {0.f, 0.f};

    int ktend = causal ? (2 * qt2 + 2) : (Tc / 64);

    const __bf16* kbase = kb + (size_t)b * Tc * ldk + h * 64 + s8;
    const __bf16* vbase = vt + (size_t)(b * 16 + h) * 64 * Tc + s8;

    bf16x8 kc0 = *(const bf16x8*)(kbase + (size_t)r0 * ldk);
    bf16x8 kc1 = *(const bf16x8*)(kbase + (size_t)r1 * ldk);
    bf16x8 vc0 = *(const bf16x8*)(vbase + (size_t)r0 * Tc);
    bf16x8 vc1 = *(const bf16x8*)(vbase + (size_t)r1 * Tc);
    bf16x8 kn0, kn1, vn0, vn1;

    for (int kt = 0; kt < ktend; ++kt) {
        __syncthreads();
        *(bf16x8*)&Ks[r0 * 72 + s8] = kc0;
        *(bf16x8*)&Ks[r1 * 72 + s8] = kc1;
        *(bf16x8*)&Vs[r0 * 72 + s8] = vc0;
        *(bf16x8*)&Vs[r1 * 72 + s8] = vc1;
        if (kt + 1 < ktend) {
            const __bf16* kp = kbase + (size_t)(kt + 1) * 64 * ldk;
            const __bf16* vp = vbase + (size_t)(kt + 1) * 64;
            kn0 = *(const bf16x8*)(kp + (size_t)r0 * ldk);
            kn1 = *(const bf16x8*)(kp + (size_t)r1 * ldk);
            vn0 = *(const bf16x8*)(vp + (size_t)r0 * Tc);
            vn1 = *(const bf16x8*)(vp + (size_t)r1 * Tc);
        }
        __syncthreads();

#pragma unroll
        for (int sub = 0; sub < 2; ++sub) {
            if (causal && kt > 2 * qt2 + sub) continue;   // wave-uniform skip

            floatx4 sacc[4] = {};
#pragma unroll
            for (int kk = 0; kk < 2; ++kk) {
                bf16x8 bq = *(const bf16x8*)&Qs[(sub * 64 + wv * 16 + l16) * 72 + kk * 32 + g16 * 8];
#pragma unroll
                for (int j = 0; j < 4; ++j) {
                    bf16x8 ak = *(const bf16x8*)&Ks[(j * 16 + l16) * 72 + kk * 32 + g16 * 8];
                    sacc[j] = __builtin_amdgcn_mfma_f32_16x16x32_bf16(ak, bq, sacc[j], 0, 0, 0);
                }
            }
            if (causal && kt == 2 * qt2 + sub) {
                int qloc = wv * 16 + l16;
#pragma unroll
                for (int j = 0; j < 4; ++j)
#pragma unroll
                    for (int r = 0; r < 4; ++r)
                        if (j * 16 + g16 * 4 + r > qloc) sacc[j][r] = -1e30f;
            }

#pragma unroll
            for (int j = 0; j < 4; ++j) {
                bf16x4 pk;
#pragma unroll
                for (int r = 0; r < 4; ++r) {
                    float p = __builtin_amdgcn_exp2f(sacc[j][r]);
                    li[sub] += p;
                    pk[r] = (__bf16)p;
                }
                *(bf16x4*)&Ps[wv][l16 * 72 + j * 16 + g16 * 4] = pk;
            }
#pragma unroll
            for (int kk = 0; kk < 2; ++kk) {
                bf16x8 bp = *(const bf16x8*)&Ps[wv][l16 * 72 + kk * 32 + g16 * 8];
#pragma unroll
                for (int j = 0; j < 4; ++j) {
                    bf16x8 av = *(const bf16x8*)&Vs[(j * 16 + l16) * 72 + kk * 32 + g16 * 8];
                    oacc[sub][j] = __builtin_amdgcn_mfma_f32_16x16x32_bf16(av, bp, oacc[sub][j], 0, 0, 0);
                }
            }
        }
        kc0 = kn0; kc1 = kn1; vc0 = vn0; vc1 = vn1;
    }

    li[0] += __shfl_xor(li[0], 16); li[0] += __shfl_xor(li[0], 32);
    li[1] += __shfl_xor(li[1], 16); li[1] += __shfl_xor(li[1], 32);

    // transpose O^T -> O through LDS (reuse Ks; per-wave slice, in-order)
    __syncthreads();
    int rw = lane >> 2, c4 = (lane & 3) * 16;
#pragma unroll
    for (int sub = 0; sub < 2; ++sub) {
        float inv = 1.f / li[sub];
#pragma unroll
        for (int j = 0; j < 4; ++j) {
            bf16x4 ok;
#pragma unroll
            for (int r = 0; r < 4; ++r) ok[r] = (__bf16)(oacc[sub][j][r] * inv);
            *(bf16x4*)&Ks[(wv * 16 + l16) * 72 + j * 16 + g16 * 4] = ok;
        }
        bf16x8 o0 = *(const bf16x8*)&Ks[(wv * 16 + rw) * 72 + c4];
        bf16x8 o1 = *(const bf16x8*)&Ks[(wv * 16 + rw) * 72 + c4 + 8];
        size_t ob = (size_t)(b * T + qt2 * 128 + sub * 64 + wv * 16 + rw) * EMB + h * 64 + c4;
        *(bf16x8*)&out[ob]     = o0;
        *(bf16x8*)&out[ob + 8] = o1;
    }
}

// --------------------------- residual + bf16 split-K partials + layernorm
// Residual chain in bf16 (R9, kept; extended to ln1 this round): ln1 now
// reads xb (the bf16 cast of x that already exists) as its residual base —
// same precision class as the accepted R9 change, -8 MB of fp32 reads.
// ln2 updates x1b in place (per-thread read-before-write). RT = residual
// element type.
template <typename RT>
__launch_bounds__(256)
__global__ void ln_kernel(const RT* res,
                          const __bf16* __restrict__ pb, int np,
                          const float* __restrict__ g, const float* __restrict__ be,
                          float* outf, __bf16* outb) {
    __shared__ float red[8];
    int row = blockIdx.x, tid = threadIdx.x;
    size_t base = (size_t)row * EMB;
    float4 v;
    if constexpr (sizeof(RT) == 4) {
        v = ((const float4*)(res + base))[tid];
    } else {
        bf16x4 rv = *(const bf16x4*)(res + base + tid * 4);
        v.x = (float)rv[0]; v.y = (float)rv[1];
        v.z = (float)rv[2]; v.w = (float)rv[3];
    }
    for (int i = 0; i < np; ++i) {
        bf16x4 u = *(const bf16x4*)(pb + i * PSTRIDE + base + tid * 4);
        v.x += (float)u[0]; v.y += (float)u[1];
        v.z += (float)u[2]; v.w += (float)u[3];
    }
    float s  = v.x + v.y + v.z + v.w;
    float ss = v.x * v.x + v.y * v.y + v.z * v.z + v.w * v.w;
#pragma unroll
    for (int o = 1; o < 64; o <<= 1) { s += __shfl_xor(s, o); ss += __shfl_xor(ss, o); }
    if ((tid & 63) == 0) { red[(tid >> 6) * 2] = s; red[(tid >> 6) * 2 + 1] = ss; }
    __syncthreads();
    s  = red[0] + red[2] + red[4] + red[6];
    ss = red[1] + red[3] + red[5] + red[7];
    float mu  = s * (1.0f / 1024.0f);
    float var = ss * (1.0f / 1024.0f) - mu * mu;
    float rs  = rsqrtf(var + 1e-5f);
    float4 gg = ((const float4*)g)[tid];
    float4 bb = ((const float4*)be)[tid];
    float4 y;
    y.x = (v.x - mu) * rs * gg.x + bb.x;
    y.y = (v.y - mu) * rs * gg.y + bb.y;
    y.z = (v.z - mu) * rs * gg.z + bb.z;
    y.w = (v.w - mu) * rs * gg.w + bb.w;
    if (outf) ((float4*)(outf + base))[tid] = y;
    if (outb) {
        bf16x4 o;
        o[0] = (__bf16)y.x; o[1] = (__bf16)y.y; o[2] = (__bf16)y.z; o[3] = (__bf16)y.w;
        *(bf16x4*)(outb + base + tid * 4) = o;
    }
}

// ---------------------------------------------------------------- launch
extern "C" void kernel_launch(void* const* d_in, const int* in_sizes, int n_in,
                              void* d_out, int out_size, void* d_ws, size_t ws_size,
                              hipStream_t stream) {
    const float* x     = (const float*)d_in[0];
    const float* ctx   = (const float*)d_in[1];
    const float* sa_wq = (const float*)d_in[2];
    const float* sa_wk = (const float*)d_in[3];
    const float* sa_wv = (const float*)d_in[4];
    const float* sa_wo = (const float*)d_in[5];
    const float* sa_bo = (const float*)d_in[6];
    const float* ca_wq = (const float*)d_in[7];
    const float* ca_wk = (const float*)d_in[8];
    const float* ca_wv = (const float*)d_in[9];
    const float* ca_wo = (const float*)d_in[10];
    const float* ca_bo = (const float*)d_in[11];
    const float* n1_g = (const float*)d_in[12];
    const float* n1_b = (const float*)d_in[13];
    const float* n2_g = (const float*)d_in[14];
    const float* n2_b = (const float*)d_in[15];
    const float* n3_g = (const float*)d_in[16];
    const float* n3_b = (const float*)d_in[17];
    const float* ff_w1 = (const float*)d_in[18];
    const float* ff_b1 = (const float*)d_in[19];
    const float* ff_w2 = (const float*)d_in[20];
    const float* ff_b2 = (const float*)d_in[21];

    size_t off = 0;
    auto alloc = [&](size_t bytes) {
        void* p = (char*)d_ws + off;
        off += (bytes + 255) & ~(size_t)255;
        return p;
    };
    __bf16* w_sa_qkvT = (__bf16*)alloc((size_t)3 * EMB * EMB * 2);  // [q;k;v]
    __bf16* w_sa_oT   = (__bf16*)alloc((size_t)EMB * EMB * 2);
    __bf16* w_ca_kvqT = (__bf16*)alloc((size_t)3 * EMB * EMB * 2);  // [k;v;q]
    __bf16* w_ca_oT   = (__bf16*)alloc((size_t)EMB * EMB * 2);
    __bf16* w1T       = (__bf16*)alloc((size_t)HIDN * EMB * 2);
    __bf16* w2T       = (__bf16*)alloc((size_t)EMB * HIDN * 2);
    __bf16* xb        = (__bf16*)alloc((size_t)MROWS * EMB * 2);     // 8 MB
    __bf16* qkv       = (__bf16*)alloc((size_t)MROWS * 3 * EMB * 2); // 24 MB, adjacent
    __bf16* ao        = (__bf16*)alloc((size_t)MROWS * EMB * 2);     // 8 MB
    __bf16* hid       = (__bf16*)alloc((size_t)MROWS * HIDN * 2);    // 32 MB
    __bf16* x1b       = (__bf16*)alloc((size_t)MROWS * EMB * 2);     // 8 MB
    __bf16* vt        = (__bf16*)alloc((size_t)MROWS * EMB * 2);     // 8 MB
    __bf16* ctxb      = (__bf16*)alloc((size_t)MROWS * EMB * 2);     // 8 MB

    __bf16* qkvc = qkv;              // CA merged output [k|v|q] (reuses qkv)
    __bf16* pbo  = qkv;              // attn-proj split-K partials (2x8MB)
    __bf16* pbf  = xb;               // ff2 partials (4x8MB over xb+qkv)
    // residual chain lives in x1b (bf16): ln1 y -> x1b; ln2 reads x1b,
    // updates in place; ln3 reads x1b. No fp32 res buffers.

    // Q pre-scale: (1024^-0.25)^2 * log2(e) — softmax runs in exp2 domain
    const float QSC = 0.04508422002778011f;
    const int   BIG = 1 << 30;
    dim3 tb(32, 8);

    // ---- all weight transposes in ONE dispatch (16 jobs) ----
    TJobs tj;
    tj.s[0] = sa_wq; tj.d[0] = w_sa_qkvT;                          tj.sld[0] = EMB;  tj.dld[0] = EMB;
    tj.s[1] = sa_wk; tj.d[1] = w_sa_qkvT + (size_t)EMB * EMB;      tj.sld[1] = EMB;  tj.dld[1] = EMB;
    tj.s[2] = sa_wv; tj.d[2] = w_sa_qkvT + (size_t)2 * EMB * EMB;  tj.sld[2] = EMB;  tj.dld[2] = EMB;
    tj.s[3] = sa_wo; tj.d[3] = w_sa_oT;                            tj.sld[3] = EMB;  tj.dld[3] = EMB;
    tj.s[4] = ca_wk; tj.d[4] = w_ca_kvqT;                          tj.sld[4] = EMB;  tj.dld[4] = EMB;
    tj.s[5] = ca_wv; tj.d[5] = w_ca_kvqT + (size_t)EMB * EMB;      tj.sld[5] = EMB;  tj.dld[5] = EMB;
    tj.s[6] = ca_wq; tj.d[6] = w_ca_kvqT + (size_t)2 * EMB * EMB;  tj.sld[6] = EMB;  tj.dld[6] = EMB;
    tj.s[7] = ca_wo; tj.d[7] = w_ca_oT;                            tj.sld[7] = EMB;  tj.dld[7] = EMB;
    for (int c = 0; c < 4; ++c) {   // ff_w1 [1024][4096] -> w1T [4096][1024]
        tj.s[8 + c] = ff_w1 + (size_t)c * 1024;
        tj.d[8 + c] = w1T + (size_t)c * 1024 * 1024;
        tj.sld[8 + c] = HIDN; tj.dld[8 + c] = EMB;
    }
    for (int c = 0; c < 4; ++c) {   // ff_w2 [4096][1024] -> w2T [1024][4096]
        tj.s[12 + c] = ff_w2 + (size_t)c * 1024 * 1024;
        tj.d[12 + c] = w2T + (size_t)c * 1024;
        tj.sld[12 + c] = EMB; tj.dld[12 + c] = HIDN;
    }
    transpose_cast16_kernel<<<dim3(32, 32, 16), tb, 0, stream>>>(tj);

    // ---- both activation casts in one dispatch ----
    cast2_bf16_kernel<<<8192, 256, 0, stream>>>(x, ctx, xb, ctxb, MROWS * EMB);

    // ---- self attention ----
    gemm256<0><<<192, 512, 0, stream>>>(xb, xb, BIG, w_sa_qkvT,
        qkv, nullptr, nullptr, MROWS, 3 * EMB, EMB, QSC, 1.f, 1024, 6, vt, 2048);
    attn_kernel<<<512, 256, 0, stream>>>(qkv, qkv + EMB, vt, 3 * EMB, 3 * EMB, ao, 1, 1024);
    gemm_bt<0, 1><<<dim3(8, 32, 2), 256, 0, stream>>>(ao, ao, BIG, w_sa_oT,
        pbo, pbo + PSTRIDE, sa_bo, MROWS, EMB, EMB, 1.f, 1.f, 0, 2, 2);
    ln_kernel<__bf16><<<4096, 256, 0, stream>>>(xb, pbo, 2, n1_g, n1_b, nullptr, x1b);

    // ---- cross attention ----
    gemm256<0><<<192, 512, 0, stream>>>(ctxb, x1b, 2048, w_ca_kvqT,
        qkvc, nullptr, nullptr, MROWS, 3 * EMB, EMB, 1.f, QSC, 2048, 6, vt, 1024);
    attn_kernel<<<512, 256, 0, stream>>>(qkvc + 2 * EMB, qkvc, vt, 3 * EMB, 3 * EMB, ao, 0, 1024);
    gemm_bt<0, 1><<<dim3(8, 32, 2), 256, 0, stream>>>(ao, ao, BIG, w_ca_oT,
        pbo, pbo + PSTRIDE, ca_bo, MROWS, EMB, EMB, 1.f, 1.f, 0, 2, 2);
    ln_kernel<__bf16><<<4096, 256, 0, stream>>>(x1b, pbo, 2, n2_g, n2_b, nullptr, x1b);

    // ---- FFN ----
    gemm256<1><<<256, 512, 0, stream>>>(x1b, x1b, BIG, w1T,
        hid, nullptr, ff_b1, MROWS, HIDN, EMB, 1.f, 1.f, 0, 8, nullptr, BIG);
    gemm256<0><<<dim3(64, 4), 512, 0, stream>>>(hid, hid, BIG, w2T,
        pbf, pbf + PSTRIDE, ff_b2, MROWS, EMB, HIDN, 1.f, 1.f, 0, 2, nullptr, BIG);
    ln_kernel<__bf16><<<4096, 256, 0, stream>>>(x1b, pbf, 4, n3_g, n3_b, (float*)d_out, nullptr);
}